// Round 2
// baseline (444.513 us; speedup 1.0000x reference)
//
#include <hip/hip_runtime.h>
#include <hip/hip_cooperative_groups.h>

namespace cg = cooperative_groups;

#define T_TOK 16384
#define E_EXP 16
#define CAP   2048
#define D_DIM 2048
#define NBLK  1024           // cooperative grid: 4 blocks/CU on 256 CUs
#define TPB   16             // tokens per block
#define NZERO 128            // tail-zeroing blocks (8 per expert)

typedef float vf4 __attribute__((ext_vector_type(4)));

__global__ __launch_bounds__(256, 4) void fused_kernel(
    const float* __restrict__ in_flow,
    const int*   __restrict__ hot_mask,
    const float* __restrict__ score,
    int*         __restrict__ counts_T,   // [E][NBLK] workspace
    float*       __restrict__ loads_out,  // [E] float (d_out tail)
    float*       __restrict__ out)        // [E*CAP, D]
{
    const int b   = blockIdx.x;
    const int tid = threadIdx.x;

    __shared__ int   s_hm[TPB][E_EXP + 1];     // token x expert membership
    __shared__ int   s_mask[E_EXP];            // 16-bit token mask per expert
    __shared__ int   s_part_pref[E_EXP][17];   // phase-2 partial prefixes
    __shared__ int   s_part_tot [E_EXP][17];   // phase-2 partial totals
    __shared__ int   s_co[E_EXP];              // exclusive chunk offset
    __shared__ int   s_tot[E_EXP];             // per-expert grand total
    __shared__ int   s_dst[TPB][2];            // per-token dest slots (-1 = none)
    __shared__ float s_g[TPB][2];              // per-token gates

    // ---- Phase 1: this chunk's membership + per-expert counts ----
    // tid -> (token tid>>4, expert tid&15); load is fully coalesced.
    s_hm[tid >> 4][tid & 15] = hot_mask[b * 256 + tid] > 0;
    __syncthreads();
    if (tid < E_EXP) {
        int m = 0;
        #pragma unroll
        for (int tl = 0; tl < TPB; ++tl) m |= s_hm[tl][tid] << tl;
        s_mask[tid] = m;
        counts_T[tid * NBLK + b] = __popc(m);
    }

    cg::this_grid().sync();   // counts_T globally visible

    // ---- Phase 2: redundant per-block exclusive prefix over chunks ----
    // thread (e = tid>>4, seg = tid&15) strides the L2-resident counts row.
    {
        const int e   = tid >> 4;
        const int seg = tid & 15;
        const int* ce = counts_T + e * NBLK;
        int pref = 0, tot = 0;
        #pragma unroll 4
        for (int c = seg; c < NBLK; c += 16) {   // coalesced within 16-lane group
            const int v = ce[c];
            tot  += v;
            pref += (c < b) ? v : 0;
        }
        s_part_pref[e][seg] = pref;
        s_part_tot [e][seg] = tot;
    }
    __syncthreads();
    if (tid < E_EXP) {
        int pref = 0, tot = 0;
        #pragma unroll
        for (int s = 0; s < 16; ++s) {
            pref += s_part_pref[tid][s];
            tot  += s_part_tot [tid][s];
        }
        s_co[tid]  = pref;
        s_tot[tid] = tot;
        if (b == 0) loads_out[tid] = (float)(tot < CAP ? tot : CAP);
    }
    __syncthreads();

    // ---- Phase 3: per-token destination slots (token order preserved:
    //      chunk-major, then mask-bit order == token order within chunk) ----
    if (tid < TPB) {
        const int tl = tid;
        const int t  = b * TPB + tl;
        int   d0 = -1, d1 = -1;
        float g0 = 0.f, g1 = 0.f;
        int   k = 0;
        #pragma unroll
        for (int e = 0; e < E_EXP; ++e) {
            const int m = s_mask[e];
            if ((m >> tl) & 1) {
                const int pos  = s_co[e] + __popc(m & ((1 << tl) - 1));
                const int slot = (pos < CAP) ? e * CAP + pos : -1;  // capacity drop
                const float sc = score[t * E_EXP + e];
                if (k == 0)      { d0 = slot; g0 = sc; }
                else if (k == 1) { d1 = slot; g1 = sc; }
                ++k;
            }
        }
        s_dst[tl][0] = d0; s_dst[tl][1] = d1;
        s_g[tl][0]   = g0; s_g[tl][1]   = g1;
    }
    __syncthreads();

    // ---- Phase 4: gather + scale; each row read from HBM exactly once ----
    for (int tl = 0; tl < TPB; ++tl) {
        const int d0 = s_dst[tl][0];
        const int d1 = s_dst[tl][1];
        if (d0 < 0 && d1 < 0) continue;          // uniform branch (LDS value)
        const vf4* irow = (const vf4*)(in_flow + (size_t)(b * TPB + tl) * D_DIM);
        const vf4 v0 = __builtin_nontemporal_load(irow + tid);
        const vf4 v1 = __builtin_nontemporal_load(irow + tid + 256);
        if (d0 >= 0) {
            const float g = s_g[tl][0];
            vf4* o = (vf4*)(out + (size_t)d0 * D_DIM);
            __builtin_nontemporal_store(v0 * g, o + tid);
            __builtin_nontemporal_store(v1 * g, o + tid + 256);
        }
        if (d1 >= 0) {
            const float g = s_g[tl][1];
            vf4* o = (vf4*)(out + (size_t)d1 * D_DIM);
            __builtin_nontemporal_store(v0 * g, o + tid);
            __builtin_nontemporal_store(v1 * g, o + tid + 256);
        }
    }

    // ---- Phase 5: zero invalid tail slots [load_e, CAP) ----
    if (b < NZERO) {
        const int e  = b >> 3, p = b & 7;
        const int ld = min(s_tot[e], CAP);       // locally computed, no round-trip
        const vf4 z = {0.f, 0.f, 0.f, 0.f};
        for (int s = ld + p; s < CAP; s += 8) {
            vf4* o = (vf4*)(out + ((size_t)e * CAP + s) * D_DIM);
            __builtin_nontemporal_store(z, o + tid);
            __builtin_nontemporal_store(z, o + tid + 256);
        }
    }
}

extern "C" void kernel_launch(void* const* d_in, const int* in_sizes, int n_in,
                              void* d_out, int out_size, void* d_ws, size_t ws_size,
                              hipStream_t stream) {
    const float* in_flow  = (const float*)d_in[0];
    const int*   hot_mask = (const int*)d_in[1];
    const float* score    = (const float*)d_in[2];

    float* out       = (float*)d_out;
    float* loads_out = out + (size_t)E_EXP * CAP * D_DIM;

    int* counts_T = (int*)d_ws;   // 16 * 1024 * 4 B = 64 KB

    void* args[] = { (void*)&in_flow, (void*)&hot_mask, (void*)&score,
                     (void*)&counts_T, (void*)&loads_out, (void*)&out };
    hipLaunchCooperativeKernel(reinterpret_cast<void*>(fused_kernel),
                               dim3(NBLK), dim3(256), args, 0, stream);
}

// Round 4
// 361.470 us; speedup vs baseline: 1.2297x; 1.2297x over previous
//
#include <hip/hip_runtime.h>

#define T_TOK 16384
#define E_EXP 16
#define CAP   2048
#define D_DIM 2048
#define NCHUNK (T_TOK / 256)   // 64 chunks of 256 tokens
#define NZERO  128             // tail-zeroing blocks (8 per expert)

typedef float vf4 __attribute__((ext_vector_type(4)));

// ---------- K1: per-chunk per-expert counts (64 blocks x 256 thr) ----------
__global__ __launch_bounds__(256) void count_kernel(
    const int* __restrict__ hot_mask,   // [T, E]
    int*       __restrict__ counts)     // [NCHUNK, E]
{
    const int chunk = blockIdx.x;
    const int tid   = threadIdx.x;
    const int t     = chunk * 256 + tid;
    const int lane  = tid & 63;
    const int wv    = tid >> 6;

    const int4* row = (const int4*)(hot_mask + (size_t)t * E_EXP);
    int4 r0 = row[0], r1 = row[1], r2 = row[2], r3 = row[3];
    int hm[16] = { r0.x > 0, r0.y > 0, r0.z > 0, r0.w > 0,
                   r1.x > 0, r1.y > 0, r1.z > 0, r1.w > 0,
                   r2.x > 0, r2.y > 0, r2.z > 0, r2.w > 0,
                   r3.x > 0, r3.y > 0, r3.z > 0, r3.w > 0 };

    __shared__ int wcnt[4][16];
    #pragma unroll
    for (int e = 0; e < 16; ++e) {
        unsigned long long m = __ballot(hm[e]);
        if (lane == 0) wcnt[wv][e] = __popcll(m);
    }
    __syncthreads();
    if (tid < 16)
        counts[chunk * E_EXP + tid] =
            wcnt[0][tid] + wcnt[1][tid] + wcnt[2][tid] + wcnt[3][tid];
}

// ---------- K2: fused scan + fill (64 blocks x 256 thr) --------------------
// Parallel exclusive chunk-scan (16 experts x 16 segments of 4 chunks each),
// then per-token destination slots + gates (token-driven layout).
__global__ __launch_bounds__(256) void scanfill_kernel(
    const int*   __restrict__ hot_mask,
    const float* __restrict__ score,
    const int*   __restrict__ counts,     // [NCHUNK, E]
    int*         __restrict__ dst2,       // [T, 2] slot index or -1
    float*       __restrict__ g2,         // [T, 2]
    int*         __restrict__ loads_i,    // [E]
    float*       __restrict__ loads_out)  // [E] float (d_out tail)
{
    const int chunk = blockIdx.x;
    const int tid   = threadIdx.x;
    const int t     = chunk * 256 + tid;
    const int lane  = tid & 63;
    const int wv    = tid >> 6;

    __shared__ int s_pp[16][17];   // partial prefix  [expert][segment]
    __shared__ int s_pt[16][17];   // partial total   [expert][segment]
    __shared__ int s_off[16];      // exclusive chunk offset per expert
    __shared__ int wcnt[4][16];

    // ---- parallel chunk scan: e = tid&15, seg = tid>>4 owns 4 chunks ----
    {
        const int e   = tid & 15;
        const int seg = tid >> 4;
        int pref = 0, tot = 0;
        #pragma unroll
        for (int i = 0; i < 4; ++i) {
            const int c = seg * 4 + i;
            const int v = counts[c * E_EXP + e];   // coalesced per 16-lane group
            tot  += v;
            pref += (c < chunk) ? v : 0;
        }
        s_pp[e][seg] = pref;
        s_pt[e][seg] = tot;
    }

    // ---- membership + scores for this chunk (independent of the scan) ----
    const int4* mrow = (const int4*)(hot_mask + (size_t)t * E_EXP);
    int4 r0 = mrow[0], r1 = mrow[1], r2 = mrow[2], r3 = mrow[3];
    int hm[16] = { r0.x > 0, r0.y > 0, r0.z > 0, r0.w > 0,
                   r1.x > 0, r1.y > 0, r1.z > 0, r1.w > 0,
                   r2.x > 0, r2.y > 0, r2.z > 0, r2.w > 0,
                   r3.x > 0, r3.y > 0, r3.z > 0, r3.w > 0 };

    const float4* srow = (const float4*)(score + (size_t)t * E_EXP);
    float4 s0 = srow[0], s1 = srow[1], s2 = srow[2], s3 = srow[3];
    float sc[16] = { s0.x, s0.y, s0.z, s0.w, s1.x, s1.y, s1.z, s1.w,
                     s2.x, s2.y, s2.z, s2.w, s3.x, s3.y, s3.z, s3.w };

    int before[16];
    const unsigned long long lmask = (1ULL << lane) - 1ULL;
    #pragma unroll
    for (int e = 0; e < 16; ++e) {
        unsigned long long m = __ballot(hm[e]);
        before[e] = __popcll(m & lmask);
        if (lane == 0) wcnt[wv][e] = __popcll(m);
    }
    __syncthreads();

    if (tid < 16) {
        int pref = 0, tot = 0;
        #pragma unroll
        for (int s = 0; s < 16; ++s) { pref += s_pp[tid][s]; tot += s_pt[tid][s]; }
        s_off[tid] = pref;
        if (chunk == 0) {
            const int ld = tot < CAP ? tot : CAP;
            loads_i[tid]   = ld;
            loads_out[tid] = (float)ld;
        }
    }
    __syncthreads();

    // token order preserved: chunk-major, then wave, then lane
    int   d0 = -1, d1 = -1;
    float gg0 = 0.f, gg1 = 0.f;
    int   k = 0;
    #pragma unroll
    for (int e = 0; e < 16; ++e) {
        if (hm[e]) {
            int woff = 0;
            for (int w = 0; w < 4; ++w) if (w < wv) woff += wcnt[w][e];
            const int pos  = s_off[e] + woff + before[e];
            const int slot = (pos < CAP) ? e * CAP + pos : -1;  // capacity drop
            if (k == 0)      { d0 = slot; gg0 = sc[e]; }
            else if (k == 1) { d1 = slot; gg1 = sc[e]; }
            ++k;
        }
    }
    ((int2*)dst2)[t]  = make_int2(d0, d1);
    ((float2*)g2)[t]  = make_float2(gg0, gg1);
}

// ---------- K3: token-driven gather + tail zero (128 + T blocks) -----------
__global__ __launch_bounds__(256) void gather_kernel(
    const float* __restrict__ in_flow,
    const int*   __restrict__ dst2,
    const float* __restrict__ g2,
    const int*   __restrict__ loads_i,
    float*       __restrict__ out)
{
    const int b   = blockIdx.x;
    const int tid = threadIdx.x;

    if (b < NZERO) {
        const int e = b >> 3, p = b & 7;
        const int ld = loads_i[e];
        const vf4 z = {0.f, 0.f, 0.f, 0.f};
        for (int s = ld + p; s < CAP; s += 8) {
            vf4* o = (vf4*)(out + ((size_t)e * CAP + s) * D_DIM);
            __builtin_nontemporal_store(z, o + tid);
            __builtin_nontemporal_store(z, o + tid + 256);
        }
        return;
    }

    const int t  = b - NZERO;
    const int d0 = dst2[2 * t];
    const int d1 = dst2[2 * t + 1];
    if (d0 < 0 && d1 < 0) return;   // token fully dropped: skip the read

    const vf4* irow = (const vf4*)(in_flow + (size_t)t * D_DIM);
    vf4 v0 = __builtin_nontemporal_load(irow + tid);
    vf4 v1 = __builtin_nontemporal_load(irow + tid + 256);

    if (d0 >= 0) {
        const float g = g2[2 * t];
        vf4* o = (vf4*)(out + (size_t)d0 * D_DIM);
        __builtin_nontemporal_store(v0 * g, o + tid);
        __builtin_nontemporal_store(v1 * g, o + tid + 256);
    }
    if (d1 >= 0) {
        const float g = g2[2 * t + 1];
        vf4* o = (vf4*)(out + (size_t)d1 * D_DIM);
        __builtin_nontemporal_store(v0 * g, o + tid);
        __builtin_nontemporal_store(v1 * g, o + tid + 256);
    }
}

extern "C" void kernel_launch(void* const* d_in, const int* in_sizes, int n_in,
                              void* d_out, int out_size, void* d_ws, size_t ws_size,
                              hipStream_t stream) {
    const float* in_flow  = (const float*)d_in[0];
    const int*   hot_mask = (const int*)d_in[1];
    const float* score    = (const float*)d_in[2];

    float* out       = (float*)d_out;
    float* loads_out = out + (size_t)E_EXP * CAP * D_DIM;

    char* ws = (char*)d_ws;
    int*   counts  = (int*)ws;   ws += NCHUNK * E_EXP * sizeof(int);
    int*   loads_i = (int*)ws;   ws += 64 * sizeof(int);
    int*   dst2    = (int*)ws;   ws += (size_t)T_TOK * 2 * sizeof(int);
    float* g2      = (float*)ws;

    count_kernel<<<NCHUNK, 256, 0, stream>>>(hot_mask, counts);
    scanfill_kernel<<<NCHUNK, 256, 0, stream>>>(hot_mask, score, counts,
                                                dst2, g2, loads_i, loads_out);
    gather_kernel<<<T_TOK + NZERO, 256, 0, stream>>>(in_flow, dst2, g2,
                                                     loads_i, out);
}